// Round 3
// baseline (230.240 us; speedup 1.0000x reference)
//
#include <hip/hip_runtime.h>
#include <hip/hip_bf16.h>
#include <math.h>

#define T_LEN 20000
#define HID 150
#define STR 168   // LDS row stride (shorts) for U/V/P/X1/h1

typedef __attribute__((ext_vector_type(8))) __bf16 bf16x8;
typedef __attribute__((ext_vector_type(4))) float f32x4;

__device__ __forceinline__ short f2bf(float f) {
    unsigned u = __float_as_uint(f);
    u = (u + 0x7fff + ((u >> 16) & 1)) >> 16;
    return (short)u;
}

__device__ __forceinline__ unsigned pk2(float a, float b) {
    __hip_bfloat162 h = __float22bfloat162_rn(make_float2(a, b));
    return *(unsigned*)&h;
}

__device__ __forceinline__ bf16x8 cvt8(float4 a, float4 b) {
    union { unsigned u[4]; bf16x8 v; } r;
    r.u[0] = pk2(a.x, a.y);
    r.u[1] = pk2(a.z, a.w);
    r.u[2] = pk2(b.x, b.y);
    r.u[3] = pk2(b.z, b.w);
    return r.v;
}

__device__ __forceinline__ float2 ubf2(unsigned u) {
    return make_float2(__uint_as_float(u << 16),
                       __uint_as_float(u & 0xffff0000u));
}

// ---------------------------------------------------------------------------
// Fragment-order weight regions (shorts), lane = consuming lane (ml|kg<<4):
//   fragA  [0,199680)        30 tiles x 13 ks x 64 x 8   U(0-9) V(10-19) aW1(20-29)
//   fragP  [199680,250880)   10 tiles x 10 ks x 64 x 8   sc_W1 rows 800..1099
//   fragAt2[250880,276480)   10 tiles x  5 ks x 64 x 8   attn_W2
//   fragW2 [276480,302080)   10 tiles x  5 ks x 64 x 8   sc_W2
// frag[((tile*KS+ks)*64+lane)*8+e] = W[k=ks*32+(lane>>4)*8+e][col=tile*16+(lane&15)]
// ---------------------------------------------------------------------------
__global__ __launch_bounds__(256) void wprep(
    const float* __restrict__ sc_W1, const float* __restrict__ attn_W1,
    const float* __restrict__ attn_W2, const float* __restrict__ sc_W2,
    short* __restrict__ frag)
{
    int t = blockIdx.x * 256 + threadIdx.x;
    if (t >= 302080) return;
    float v = 0.f;
    if (t < 199680) {
        int e = t & 7, g = t >> 3;
        int lane = g & 63, h = g >> 6;
        int ks = h % 13, nt = h / 13;
        int k = ks * 32 + (lane >> 4) * 8 + e;
        int cs = (nt % 10) * 16 + (lane & 15);
        if (k < 400 && cs < HID) {
            if (nt < 10)      v = sc_W1[(long)k * HID + cs];
            else if (nt < 20) v = sc_W1[(long)(400 + k) * HID + cs];
            else              v = attn_W1[(long)k * HID + cs];
        }
    } else if (t < 250880) {
        int r = t - 199680;
        int e = r & 7, g = r >> 3;
        int lane = g & 63, h = g >> 6;
        int ks = h % 10, nt = h / 10;
        int k = ks * 32 + (lane >> 4) * 8 + e;
        int cs = nt * 16 + (lane & 15);
        if (k < 300 && cs < HID) v = sc_W1[(long)(800 + k) * HID + cs];
    } else if (t < 276480) {
        int r = t - 250880;
        int e = r & 7, g = r >> 3;
        int lane = g & 63, h = g >> 6;
        int ks = h % 5, nt = h / 5;
        int k = ks * 32 + (lane >> 4) * 8 + e;
        int cs = nt * 16 + (lane & 15);
        if (k < HID && cs < HID) v = attn_W2[(long)k * HID + cs];
    } else {
        int r = t - 276480;
        int e = r & 7, g = r >> 3;
        int lane = g & 63, h = g >> 6;
        int ks = h % 5, nt = h / 5;
        int k = ks * 32 + (lane >> 4) * 8 + e;
        int cs = nt * 16 + (lane & 15);
        if (k < HID && cs < HID) v = sc_W2[(long)k * HID + cs];
    }
    frag[t] = f2bf(v);
}

// ---------------------------------------------------------------------------
// mega: ONE kernel for the whole pipeline. Grid 625, 384 threads (6 waves).
// Block x owns spans s0=32x .. s0+31 (all widths 1..10). It needs U rows
// s0..s0+31 and V/P/X1/logits rows s0..s0+41 ONLY -> computes 48 (clamped)
// local rows of everything directly into LDS (identical bf16 rounding as the
// old global round-trip => bit-identical results), then runs the span loop
// with a wave role-split: waves 0-3 do the scorer MFMAs for width n while
// waves 4-5 do attention-pool phase1 for width n+1 from LDS-resident P/V.
// Eliminates: 19.2 MB Ubf/Vbf/Pbf HBM writes + all span-phase global reads
// + one kernel launch + the width-6..10 prefix redundancy.
// ---------------------------------------------------------------------------
__global__ __launch_bounds__(384) void mega(
    const float* __restrict__ states, const float* __restrict__ embeds,
    const short* __restrict__ frag,
    const float* __restrict__ scb1, const float* __restrict__ ab1,
    const float* __restrict__ ab2, const float* __restrict__ aW3,
    const float* __restrict__ ab3,
    const float* __restrict__ b2, const float* __restrict__ W3,
    const float* __restrict__ b3,
    float* __restrict__ out)
{
    __shared__ short AsU[19968];        // 39,936 B: A fragments; later h1s[2][32*STR]
    __shared__ short Us[32 * STR];      // U rows 0..31   (bf16, +sc_b1)
    __shared__ short Vs[48 * STR];      // V rows 0..47
    __shared__ short Ps[48 * STR];      // P rows 0..47
    __shared__ short X1s[48 * STR];     // relu(states@aW1+ab1) rows 0..47
    __shared__ float redl[48][6];
    __shared__ float reds[2][32][2];
    __shared__ float Ls[48], ebuf[48];
    __shared__ float sb1[160], ab1s[160], b2s[160], W3s[160];

    const int tid = threadIdx.x;
    const int w = tid >> 6, lane = tid & 63;
    const int ml = lane & 15, kg = lane >> 4;
    const int s0 = blockIdx.x * 32;          // 625 * 32 = 20000 exact

    for (int t = tid; t < 160; t += 384) {
        sb1[t]  = (t < HID) ? scb1[t] : 0.f;
        ab1s[t] = (t < HID) ? ab1[t]  : 0.f;
        b2s[t]  = (t < HID) ? b2[t]   : 0.f;
        W3s[t]  = (t < HID) ? W3[t]   : 0.f;
    }

    // ---- stage states rows s0..s0+47 (clamped) into AsU, fragment layout ----
    // AsU[((g*13+ks)*64+lane)*8+e] = bf16(states[row(g*16+(lane&15))][ks*32+(lane>>4)*8+e])
    for (int idx = tid; idx < 2496; idx += 384) {
        int g = idx / 832, r = idx - g * 832;
        int ks = r >> 6, l2 = r & 63;
        int k = ks * 32 + ((l2 >> 4) << 3);
        int row = s0 + g * 16 + (l2 & 15); if (row > T_LEN - 1) row = T_LEN - 1;
        const float* Ar = states + (long)row * 400;
        float4 a0 = make_float4(0.f, 0.f, 0.f, 0.f), a1 = a0;
        if (k + 4 <= 400) a0 = *(const float4*)&Ar[k];
        if (k + 8 <= 400) a1 = *(const float4*)&Ar[k + 4];
        *(bf16x8*)&AsU[idx * 8] = cvt8(a0, a1);
    }
    __syncthreads();

    // ---------------- Phase A: states @ {U,V,aW1}, 48 rows ----------------
    {
        f32x4 acc[5][3];
        #pragma unroll
        for (int t = 0; t < 5; ++t)
            #pragma unroll
            for (int g = 0; g < 3; ++g)
                acc[t][g] = (f32x4){0.f, 0.f, 0.f, 0.f};

        const short* fb = frag + lane * 8;
        const int t5 = w * 5;
        bf16x8 bcur[5], bnxt[5];
        #pragma unroll
        for (int t = 0; t < 5; ++t)
            bcur[t] = *(const bf16x8*)&fb[((t5 + t) * 13) << 9];

        #pragma unroll
        for (int ks = 0; ks < 13; ++ks) {
            if (ks < 12) {
                #pragma unroll
                for (int t = 0; t < 5; ++t)
                    bnxt[t] = *(const bf16x8*)&fb[((t5 + t) * 13 + ks + 1) << 9];
            }
            bf16x8 af0 = *(const bf16x8*)&AsU[(ks * 64 + lane) * 8];
            bf16x8 af1 = *(const bf16x8*)&AsU[(832 + ks * 64 + lane) * 8];
            bf16x8 af2_ = *(const bf16x8*)&AsU[(1664 + ks * 64 + lane) * 8];
            #pragma unroll
            for (int t = 0; t < 5; ++t) {
                acc[t][0] = __builtin_amdgcn_mfma_f32_16x16x32_bf16(bcur[t], af0, acc[t][0], 0, 0, 0);
                acc[t][1] = __builtin_amdgcn_mfma_f32_16x16x32_bf16(bcur[t], af1, acc[t][1], 0, 0, 0);
                acc[t][2] = __builtin_amdgcn_mfma_f32_16x16x32_bf16(bcur[t], af2_, acc[t][2], 0, 0, 0);
            }
            #pragma unroll
            for (int t = 0; t < 5; ++t) bcur[t] = bnxt[t];
        }

        // epilogue (wave-uniform output class): w0-1 -> U, w2-3 -> V, w4-5 -> X1
        #pragma unroll
        for (int t = 0; t < 5; ++t) {
            int nt = t5 + t;
            #pragma unroll
            for (int g = 0; g < 3; ++g) {
                if (w < 2) {
                    if (g < 2) {              // U only needed for rows 0..31
                        int col0 = nt * 16 + kg * 4;
                        float v[4];
                        #pragma unroll
                        for (int r = 0; r < 4; ++r) {
                            int c = col0 + r;
                            v[r] = (c < HID) ? acc[t][g][r] + sb1[c] : 0.f;
                        }
                        *(uint2*)&Us[(g * 16 + ml) * STR + col0] =
                            make_uint2(pk2(v[0], v[1]), pk2(v[2], v[3]));
                    }
                } else if (w < 4) {
                    int col0 = (nt - 10) * 16 + kg * 4;
                    float v[4];
                    #pragma unroll
                    for (int r = 0; r < 4; ++r) {
                        int c = col0 + r;
                        v[r] = (c < HID) ? acc[t][g][r] : 0.f;
                    }
                    *(uint2*)&Vs[(g * 16 + ml) * STR + col0] =
                        make_uint2(pk2(v[0], v[1]), pk2(v[2], v[3]));
                } else {
                    int col0 = (nt - 20) * 16 + kg * 4;
                    float v[4];
                    #pragma unroll
                    for (int r = 0; r < 4; ++r) {
                        int c = col0 + r;
                        v[r] = (c < HID) ? fmaxf(acc[t][g][r] + ab1s[c], 0.f) : 0.f;
                    }
                    *(uint2*)&X1s[(g * 16 + ml) * STR + col0] =
                        make_uint2(pk2(v[0], v[1]), pk2(v[2], v[3]));
                }
            }
        }
    }
    __syncthreads();   // AsU reads done

    // ---- restage embeds rows (48, clamped) into AsU ----
    for (int idx = tid; idx < 1920; idx += 384) {
        int g = idx / 640, r = idx - g * 640;
        int ks = r >> 6, l2 = r & 63;
        int k = ks * 32 + ((l2 >> 4) << 3);
        int row = s0 + g * 16 + (l2 & 15); if (row > T_LEN - 1) row = T_LEN - 1;
        const float* Er = embeds + (long)row * 300;
        float4 a0 = make_float4(0.f, 0.f, 0.f, 0.f), a1 = a0;
        if (k + 4 <= 300) a0 = *(const float4*)&Er[k];
        if (k + 8 <= 300) a1 = *(const float4*)&Er[k + 4];
        *(bf16x8*)&AsU[idx * 8] = cvt8(a0, a1);
    }
    __syncthreads();

    // ---------------- Phase B: embeds @ P-slice, 48 rows ----------------
    const int tB = (w < 4) ? 2 * w : (w == 4 ? 8 : 9);
    const int nTP = (w < 4) ? 2 : 1;
    {
        f32x4 accP[2][3];
        #pragma unroll
        for (int t = 0; t < 2; ++t)
            #pragma unroll
            for (int g = 0; g < 3; ++g)
                accP[t][g] = (f32x4){0.f, 0.f, 0.f, 0.f};

        const short* fP = frag + 199680 + lane * 8;
        bf16x8 pcur[2], pnxt[2];
        #pragma unroll
        for (int t = 0; t < 2; ++t)
            if (t < nTP) pcur[t] = *(const bf16x8*)&fP[((tB + t) * 10) << 9];

        #pragma unroll
        for (int ks = 0; ks < 10; ++ks) {
            if (ks < 9) {
                #pragma unroll
                for (int t = 0; t < 2; ++t)
                    if (t < nTP) pnxt[t] = *(const bf16x8*)&fP[((tB + t) * 10 + ks + 1) << 9];
            }
            bf16x8 af0 = *(const bf16x8*)&AsU[(ks * 64 + lane) * 8];
            bf16x8 af1 = *(const bf16x8*)&AsU[(640 + ks * 64 + lane) * 8];
            bf16x8 af2_ = *(const bf16x8*)&AsU[(1280 + ks * 64 + lane) * 8];
            #pragma unroll
            for (int t = 0; t < 2; ++t) {
                if (t < nTP) {
                    accP[t][0] = __builtin_amdgcn_mfma_f32_16x16x32_bf16(pcur[t], af0, accP[t][0], 0, 0, 0);
                    accP[t][1] = __builtin_amdgcn_mfma_f32_16x16x32_bf16(pcur[t], af1, accP[t][1], 0, 0, 0);
                    accP[t][2] = __builtin_amdgcn_mfma_f32_16x16x32_bf16(pcur[t], af2_, accP[t][2], 0, 0, 0);
                }
            }
            #pragma unroll
            for (int t = 0; t < 2; ++t) pcur[t] = pnxt[t];
        }

        #pragma unroll
        for (int t = 0; t < 2; ++t) {
            if (t < nTP) {
                int col0 = (tB + t) * 16 + kg * 4;
                #pragma unroll
                for (int g = 0; g < 3; ++g) {
                    float v[4];
                    #pragma unroll
                    for (int r = 0; r < 4; ++r) {
                        int c = col0 + r;
                        v[r] = (c < HID) ? accP[t][g][r] : 0.f;
                    }
                    *(uint2*)&Ps[(g * 16 + ml) * STR + col0] =
                        make_uint2(pk2(v[0], v[1]), pk2(v[2], v[3]));
                }
            }
        }
    }

    // ---------------- attn layers 2+3 -> redl ----------------
    {
        const short* fAt2 = frag + 250880 + lane * 8;
        bf16x8 afx[3][5];
        #pragma unroll
        for (int g = 0; g < 3; ++g)
            #pragma unroll
            for (int ks = 0; ks < 5; ++ks)
                afx[g][ks] = *(const bf16x8*)&X1s[(g * 16 + ml) * STR + ks * 32 + kg * 8];

        float score[3][4];
        #pragma unroll
        for (int g = 0; g < 3; ++g)
            #pragma unroll
            for (int r = 0; r < 4; ++r) score[g][r] = 0.f;

        #pragma unroll
        for (int t = 0; t < 2; ++t) {
            if (t < nTP) {
                int nt = tB + t;
                bf16x8 wb[5];
                #pragma unroll
                for (int ks = 0; ks < 5; ++ks)
                    wb[ks] = *(const bf16x8*)&fAt2[(nt * 5 + ks) << 9];
                f32x4 a2[3];
                a2[0] = (f32x4){0.f, 0.f, 0.f, 0.f};
                a2[1] = (f32x4){0.f, 0.f, 0.f, 0.f};
                a2[2] = (f32x4){0.f, 0.f, 0.f, 0.f};
                #pragma unroll
                for (int g = 0; g < 3; ++g)
                    #pragma unroll
                    for (int ks = 0; ks < 5; ++ks)
                        a2[g] = __builtin_amdgcn_mfma_f32_16x16x32_bf16(afx[g][ks], wb[ks], a2[g], 0, 0, 0);
                int col = nt * 16 + ml;
                float b2v = (col < HID) ? ab2[col] : 0.f;
                float w3v = (col < HID) ? aW3[col] : 0.f;
                #pragma unroll
                for (int g = 0; g < 3; ++g)
                    #pragma unroll
                    for (int r = 0; r < 4; ++r)
                        score[g][r] += fmaxf(a2[g][r] + b2v, 0.f) * w3v;
            }
        }
        #pragma unroll
        for (int g = 0; g < 3; ++g)
            #pragma unroll
            for (int r = 0; r < 4; ++r) {
                score[g][r] += __shfl_xor(score[g][r], 1);
                score[g][r] += __shfl_xor(score[g][r], 2);
                score[g][r] += __shfl_xor(score[g][r], 4);
                score[g][r] += __shfl_xor(score[g][r], 8);
            }
        if (ml == 0) {
            #pragma unroll
            for (int g = 0; g < 3; ++g)
                #pragma unroll
                for (int r = 0; r < 4; ++r)
                    redl[g * 16 + kg * 4 + r][w] = score[g][r];
        }
    }
    __syncthreads();

    // ---------------- logits + chunk softmax (wave 0, wave-synchronous) ----
    if (tid < 48) {
        float Lv = redl[tid][0] + redl[tid][1] + redl[tid][2] +
                   redl[tid][3] + redl[tid][4] + redl[tid][5] + ab3[0];
        Ls[tid] = (tid < 41) ? Lv : -1e30f;
    }
    if (tid < 48) {
        float M = -1e30f;
        for (int t = 0; t < 41; ++t) M = fmaxf(M, Ls[t]);
        ebuf[tid] = (tid < 41) ? expf(Ls[tid] - M) : 0.f;
    }

    // ---------------- span loop, waves 4-5 = phase1, waves 0-3 = phase2 ----
    float Ur[2][20], accp[2][20], den[2];
    const int u = tid & 127;               // w>=4: tid-256
    if (w >= 4) {
        #pragma unroll
        for (int z = 0; z < 2; ++z) {
            int uz = u + z * 128;
            int iz = uz >> 3, d0z = 20 * (uz & 7);
            const uint2* U2 = (const uint2*)&Us[iz * STR + d0z];
            #pragma unroll
            for (int c = 0; c < 5; ++c) {
                uint2 uv = U2[c];
                float2 a = ubf2(uv.x), b_ = ubf2(uv.y);
                Ur[z][4 * c + 0] = a.x;  Ur[z][4 * c + 1] = a.y;
                Ur[z][4 * c + 2] = b_.x; Ur[z][4 * c + 3] = b_.y;
            }
            #pragma unroll
            for (int d = 0; d < 20; ++d) accp[z][d] = 0.f;
            den[z] = 0.f;
        }
    }
    __syncthreads();   // ebuf visible to all; AsU free for h1s overlay

    short* h1p = AsU;  // h1s[2][32*STR] overlay

    auto phase1 = [&](int n, int p) {
        #pragma unroll
        for (int z = 0; z < 2; ++z) {
            int uz = u + z * 128;
            int iz = uz >> 3, d0z = 20 * (uz & 7);
            int l = iz + n - 1;                  // local row 0..40
            float e = ebuf[l];
            den[z] += e;
            const uint2* P2 = (const uint2*)&Ps[l * STR + d0z];
            #pragma unroll
            for (int c = 0; c < 5; ++c) {
                uint2 pv = P2[c];
                float2 a = ubf2(pv.x), b_ = ubf2(pv.y);
                accp[z][4 * c + 0] += e * a.x;  accp[z][4 * c + 1] += e * a.y;
                accp[z][4 * c + 2] += e * b_.x; accp[z][4 * c + 3] += e * b_.y;
            }
            float invd = 1.f / den[z];
            const uint2* V2 = (const uint2*)&Vs[l * STR + d0z];
            #pragma unroll
            for (int c = 0; c < 5; ++c) {
                uint2 vv = V2[c];
                float2 a = ubf2(vv.x), b_ = ubf2(vv.y);
                float x0 = fmaxf(Ur[z][4 * c + 0] + a.x  + accp[z][4 * c + 0] * invd, 0.f);
                float x1 = fmaxf(Ur[z][4 * c + 1] + a.y  + accp[z][4 * c + 1] * invd, 0.f);
                float x2 = fmaxf(Ur[z][4 * c + 2] + b_.x + accp[z][4 * c + 2] * invd, 0.f);
                float x3 = fmaxf(Ur[z][4 * c + 3] + b_.y + accp[z][4 * c + 3] * invd, 0.f);
                *(uint2*)&h1p[p * (32 * STR) + iz * STR + d0z + 4 * c] =
                    make_uint2(pk2(x0, x1), pk2(x2, x3));
            }
        }
    };

    if (w >= 4) phase1(1, 0);
    __syncthreads();

    const int mt = w >> 1;            // phase2: m-tile
    const int nt0 = (w & 1) * 5;      // phase2: nt half
    const short* fW2 = frag + 276480;
    const float bb = b3[0];

    for (int n = 1; n <= 10; ++n) {
        const int p = (n - 1) & 1;
        if (w >= 4) {
            if (n < 10) phase1(n + 1, 1 - p);
        } else {
            bf16x8 af[5];
            #pragma unroll
            for (int ks = 0; ks < 5; ++ks)
                af[ks] = *(const bf16x8*)&h1p[p * (32 * STR) + (mt * 16 + ml) * STR + ks * 32 + kg * 8];

            float sc[4] = {0.f, 0.f, 0.f, 0.f};
            #pragma unroll
            for (int j = 0; j < 5; ++j) {
                int nt = nt0 + j;
                f32x4 a2 = {0.f, 0.f, 0.f, 0.f};
                #pragma unroll
                for (int ks = 0; ks < 5; ++ks) {
                    bf16x8 bf = *(const bf16x8*)&fW2[(long)(((nt * 5 + ks) << 6) | lane) << 3];
                    a2 = __builtin_amdgcn_mfma_f32_16x16x32_bf16(af[ks], bf, a2, 0, 0, 0);
                }
                int col = nt * 16 + ml;
                float b2v = b2s[col], w3v = W3s[col];
                #pragma unroll
                for (int r = 0; r < 4; ++r)
                    sc[r] += fmaxf(a2[r] + b2v, 0.f) * w3v;
            }
            #pragma unroll
            for (int r = 0; r < 4; ++r) {
                sc[r] += __shfl_xor(sc[r], 1);
                sc[r] += __shfl_xor(sc[r], 2);
                sc[r] += __shfl_xor(sc[r], 4);
                sc[r] += __shfl_xor(sc[r], 8);
            }
            if (ml == 0) {
                #pragma unroll
                for (int r = 0; r < 4; ++r)
                    reds[p][mt * 16 + kg * 4 + r][w & 1] = sc[r];
            }
        }
        __syncthreads();
        if (tid < 32) {
            int S = T_LEN - n + 1;
            int off = (n - 1) * (T_LEN + 1) - (n - 1) * n / 2;
            int sr = s0 + tid;
            if (sr < S) out[off + sr] = reds[p][tid][0] + reds[p][tid][1] + bb;
        }
    }
}

// ---------------------------------------------------------------------------
extern "C" void kernel_launch(void* const* d_in, const int* in_sizes, int n_in,
                              void* d_out, int out_size, void* d_ws, size_t ws_size,
                              hipStream_t stream) {
    const float* embeds  = (const float*)d_in[0];
    const float* states  = (const float*)d_in[1];
    const float* attn_W1 = (const float*)d_in[2];
    const float* attn_b1 = (const float*)d_in[3];
    const float* attn_W2 = (const float*)d_in[4];
    const float* attn_b2 = (const float*)d_in[5];
    const float* attn_W3 = (const float*)d_in[6];
    const float* attn_b3 = (const float*)d_in[7];
    const float* sc_W1   = (const float*)d_in[8];
    const float* sc_b1   = (const float*)d_in[9];
    const float* sc_W2   = (const float*)d_in[10];
    const float* sc_b2   = (const float*)d_in[11];
    const float* sc_W3   = (const float*)d_in[12];
    const float* sc_b3   = (const float*)d_in[13];
    float* out = (float*)d_out;

    short* frag = (short*)d_ws;               // 302,080 shorts

    wprep<<<1180, 256, 0, stream>>>(sc_W1, attn_W1, attn_W2, sc_W2, frag);
    mega<<<625, 384, 0, stream>>>(states, embeds, frag, sc_b1, attn_b1,
                                  attn_b2, attn_W3, attn_b3,
                                  sc_b2, sc_W3, sc_b3, out);
}